// Round 7
// baseline (2847827.148 us; speedup 1.0000x reference)
//
#include <hip/hip_runtime.h>

// Problem constants
#define BDIM 256   // batch
#define TDIM 256   // timesteps
#define IDIM 512   // input dim
#define HDIM 512   // hidden dim
#define G4   2048  // 4*H gate rows

typedef __attribute__((ext_vector_type(4))) float f32x4;
typedef __attribute__((ext_vector_type(8))) short short8;     // 8 bf16 MFMA frag
typedef __attribute__((ext_vector_type(8))) unsigned short u16x8;
typedef __attribute__((ext_vector_type(4))) unsigned short u16x4;
typedef unsigned long long ull;

__device__ __forceinline__ unsigned short f2bf(float f) {
  union { float f; unsigned u; } v; v.f = f;
  unsigned r = v.u + 0x7FFFu + ((v.u >> 16) & 1u);   // RNE
  return (unsigned short)(r >> 16);
}
__device__ __forceinline__ float bf2f(unsigned short h) {
  union { unsigned u; float f; } v; v.u = ((unsigned)h) << 16; return v.f;
}
__device__ __forceinline__ float sigmoidf_fast(float x) {
  return 1.0f / (1.0f + __expf(-x));
}
__device__ __forceinline__ float tanhf_fast(float x) {
  float e = __expf(2.0f * x);
  return 1.0f - 2.0f / (e + 1.0f);
}
// async global->LDS 16B DMA (dst = wave-uniform base + lane*16)
__device__ __forceinline__ void gl_lds16(const unsigned short* g, unsigned short* l) {
  __builtin_amdgcn_global_load_lds(
      (const __attribute__((address_space(1))) unsigned int*)g,
      (__attribute__((address_space(3))) unsigned int*)l, 16, 0, 0);
}

// --- sc0 (XCD-L2-coherent, L1-bypass) helpers for the fast path -------------
__device__ __forceinline__ unsigned flag_ld_sc0(const unsigned* p) {
  unsigned v;
  asm volatile("global_load_dword %0, %1, off sc0\ns_waitcnt vmcnt(0)"
               : "=v"(v) : "v"(p) : "memory");
  return v;
}
__device__ __forceinline__ void flag_st_sc0(unsigned* p, unsigned v) {
  asm volatile("global_store_dword %0, %1, off sc0" :: "v"(p), "v"(v) : "memory");
}
__device__ __forceinline__ void st8_sc0(void* p, ull v) {
  asm volatile("global_store_dwordx2 %0, %1, off sc0" :: "v"(p), "v"(v) : "memory");
}
// 8 loads + one vmcnt(0) in a single asm block (no per-load serialization,
// no compiler interleaving between issue and wait).
__device__ __forceinline__ void ld_h8x_sc0(
    const ull* p0, const ull* p1, const ull* p2, const ull* p3,
    const ull* p4, const ull* p5, const ull* p6, const ull* p7,
    ull& h0, ull& h1, ull& h2, ull& h3, ull& h4, ull& h5, ull& h6, ull& h7) {
  asm volatile(
      "global_load_dwordx2 %0, %8, off sc0\n"
      "global_load_dwordx2 %1, %9, off sc0\n"
      "global_load_dwordx2 %2, %10, off sc0\n"
      "global_load_dwordx2 %3, %11, off sc0\n"
      "global_load_dwordx2 %4, %12, off sc0\n"
      "global_load_dwordx2 %5, %13, off sc0\n"
      "global_load_dwordx2 %6, %14, off sc0\n"
      "global_load_dwordx2 %7, %15, off sc0\n"
      "s_waitcnt vmcnt(0)"
      : "=&v"(h0), "=&v"(h1), "=&v"(h2), "=&v"(h3),
        "=&v"(h4), "=&v"(h5), "=&v"(h6), "=&v"(h7)
      : "v"(p0), "v"(p1), "v"(p2), "v"(p3), "v"(p4), "v"(p5), "v"(p6), "v"(p7)
      : "memory");
}
__device__ __forceinline__ void wait_vm0() {
  asm volatile("s_waitcnt vmcnt(0)" ::: "memory");
}

// xg scatter offset shared by both GEMM epilogues.
// Layout: ((t*8 + bb)*8 + jw)*8192 + q*2048 + (b&31)*64 + jc
__device__ __forceinline__ size_t xg_off(int m, int n) {
  int b = m >> 8, t = m & 255;
  int q = n >> 9, jcol = n & 511;
  return (((size_t)t * 8 + (b >> 5)) * 8 + (jcol >> 6)) * 8192
         + (size_t)q * 2048 + (b & 31) * 64 + (jcol & 63);
}

// ---------------------------------------------------------------------------
// fp32 -> bf16 pre-convert of x (33.5M) and W_ih (1M). 8 elems/thread.
// ---------------------------------------------------------------------------
__global__ void __launch_bounds__(256) convert_bf16(
    const float* __restrict__ x, const float* __restrict__ w,
    unsigned short* __restrict__ xb, unsigned short* __restrict__ wb)
{
  const size_t NX8 = (size_t)BDIM * TDIM * IDIM / 8;   // 4194304
  const size_t NW8 = (size_t)G4 * IDIM / 8;            // 131072
  size_t idx = (size_t)blockIdx.x * 256 + threadIdx.x;
  const float4* sp; u16x8* dp; size_t i;
  if (idx < NX8)      { sp = (const float4*)x; dp = (u16x8*)xb; i = idx; }
  else if (idx < NX8 + NW8) { sp = (const float4*)w; dp = (u16x8*)wb; i = idx - NX8; }
  else return;
  float4 a = sp[i * 2], b = sp[i * 2 + 1];
  u16x8 o = { f2bf(a.x), f2bf(a.y), f2bf(a.z), f2bf(a.w),
              f2bf(b.x), f2bf(b.y), f2bf(b.z), f2bf(b.w) };
  dp[i] = o;
}

// ---------------------------------------------------------------------------
// Phase 1 (fast): m97-style bf16 GEMM, 128x128 tile, BK=32, global_load_lds 16B.
// ---------------------------------------------------------------------------
__global__ void __launch_bounds__(256, 2) xg_gemm_bf16(
    const unsigned short* __restrict__ Xb, const unsigned short* __restrict__ Wb,
    const float* __restrict__ b_ih, const float* __restrict__ b_hh,
    unsigned short* __restrict__ xg)
{
  __shared__ unsigned short sA[128 * 32];
  __shared__ unsigned short sB[128 * 32];

  const int tid  = threadIdx.x;
  const int lane = tid & 63;
  const int wave = tid >> 6;
  const int l15  = lane & 15;
  const int quad = lane >> 4;
  const int nt = blockIdx.x & 15;
  const int mt = blockIdx.x >> 4;
  const int wm = (wave >> 1) * 64;
  const int wn = (wave & 1) * 64;

  f32x4 acc[4][4];
  #pragma unroll
  for (int i = 0; i < 4; ++i)
    #pragma unroll
    for (int j = 0; j < 4; ++j)
      acc[i][j] = (f32x4){0.f, 0.f, 0.f, 0.f};

  for (int kt = 0; kt < 16; ++kt) {
    #pragma unroll
    for (int i = 0; i < 2; ++i) {
      int c   = wave * 128 + i * 64 + lane;
      int row = c >> 2, cg = c & 3;
      const unsigned short* ga = Xb + (size_t)(mt * 128 + row) * 512 + kt * 32 + cg * 8;
      gl_lds16(ga, sA + (size_t)(wave * 128 + i * 64) * 8);
      const unsigned short* gb = Wb + (size_t)(nt * 128 + row) * 512 + kt * 32 + cg * 8;
      gl_lds16(gb, sB + (size_t)(wave * 128 + i * 64) * 8);
    }
    __syncthreads();

    short8 af[4], bfr[4];
    #pragma unroll
    for (int i = 0; i < 4; ++i) {
      af[i]  = *(const short8*)&sA[(wm + i * 16 + l15) * 32 + quad * 8];
      bfr[i] = *(const short8*)&sB[(wn + i * 16 + l15) * 32 + quad * 8];
    }
    #pragma unroll
    for (int am = 0; am < 4; ++am)
      #pragma unroll
      for (int an = 0; an < 4; ++an)
        acc[am][an] = __builtin_amdgcn_mfma_f32_16x16x32_bf16(
            af[am], bfr[an], acc[am][an], 0, 0, 0);
    __syncthreads();
  }

  float biasv[4];
  #pragma unroll
  for (int an = 0; an < 4; ++an) {
    int n = nt * 128 + wn + an * 16 + l15;
    biasv[an] = b_ih[n] + b_hh[n];
  }
  #pragma unroll
  for (int am = 0; am < 4; ++am)
    #pragma unroll
    for (int reg = 0; reg < 4; ++reg) {
      int m = mt * 128 + wm + am * 16 + quad * 4 + reg;
      #pragma unroll
      for (int an = 0; an < 4; ++an) {
        int n = nt * 128 + wn + an * 16 + l15;
        xg[xg_off(m, n)] = f2bf(acc[am][an][reg] + biasv[an]);
      }
    }
}

// ---------------------------------------------------------------------------
// Phase 1 (fallback, ws too small): fp32-staging GEMM.
// ---------------------------------------------------------------------------
__global__ void __launch_bounds__(256, 2) xg_gemm_f32(
    const float* __restrict__ X, const float* __restrict__ Wih,
    const float* __restrict__ b_ih, const float* __restrict__ b_hh,
    unsigned short* __restrict__ xg)
{
  __shared__ unsigned short sA[128][40];
  __shared__ unsigned short sB[128][40];

  const int tid  = threadIdx.x;
  const int lane = tid & 63;
  const int wave = tid >> 6;
  const int l15  = lane & 15;
  const int quad = lane >> 4;
  const int nt = blockIdx.x;
  const int mt = blockIdx.y;
  const int wm = (wave >> 1) * 64;
  const int wn = (wave & 1) * 64;
  const int r    = tid >> 1;
  const int half = (tid & 1) * 16;

  const float* arow = X   + (size_t)(mt * 128 + r) * 512 + half;
  const float* brow = Wih + (size_t)(nt * 128 + r) * 512 + half;

  f32x4 acc[4][4];
  #pragma unroll
  for (int i = 0; i < 4; ++i)
    #pragma unroll
    for (int j = 0; j < 4; ++j)
      acc[i][j] = (f32x4){0.f, 0.f, 0.f, 0.f};

  for (int kt = 0; kt < 16; ++kt) {
    const float* ap = arow + kt * 32;
    const float* bp = brow + kt * 32;
    #pragma unroll
    for (int i = 0; i < 4; ++i) {
      float4 a = ((const float4*)ap)[i];
      u16x4 av = { f2bf(a.x), f2bf(a.y), f2bf(a.z), f2bf(a.w) };
      *(u16x4*)&sA[r][half + i * 4] = av;
      float4 b = ((const float4*)bp)[i];
      u16x4 bv = { f2bf(b.x), f2bf(b.y), f2bf(b.z), f2bf(b.w) };
      *(u16x4*)&sB[r][half + i * 4] = bv;
    }
    __syncthreads();
    short8 af[4], bfr[4];
    #pragma unroll
    for (int i = 0; i < 4; ++i) {
      af[i]  = *(const short8*)&sA[wm + i * 16 + l15][quad * 8];
      bfr[i] = *(const short8*)&sB[wn + i * 16 + l15][quad * 8];
    }
    #pragma unroll
    for (int am = 0; am < 4; ++am)
      #pragma unroll
      for (int an = 0; an < 4; ++an)
        acc[am][an] = __builtin_amdgcn_mfma_f32_16x16x32_bf16(
            af[am], bfr[an], acc[am][an], 0, 0, 0);
    __syncthreads();
  }

  float biasv[4];
  #pragma unroll
  for (int an = 0; an < 4; ++an) {
    int n = nt * 128 + wn + an * 16 + l15;
    biasv[an] = b_ih[n] + b_hh[n];
  }
  #pragma unroll
  for (int am = 0; am < 4; ++am)
    #pragma unroll
    for (int reg = 0; reg < 4; ++reg) {
      int m = mt * 128 + wm + am * 16 + quad * 4 + reg;
      #pragma unroll
      for (int an = 0; an < 4; ++an) {
        int n = nt * 128 + wn + an * 16 + l15;
        xg[xg_off(m, n)] = f2bf(acc[am][an][reg] + biasv[an]);
      }
    }
}

// ---------------------------------------------------------------------------
// Scan step loop, templated on coherence path.
// AG=true : agent-scope atomics, MALL coherence point (R6 proven path).
// AG=false: sc0 asm, per-XCD L2 coherence point (all 8 group members verified
//           on one XCD via HW_REG_XCC_ID handshake).
// ---------------------------------------------------------------------------
template<bool AG>
__device__ void scan_steps(
    const unsigned short* __restrict__ xg,
    unsigned short* __restrict__ hbuf0, unsigned short* __restrict__ hbuf1,
    unsigned int* flagbase, int bb, int jw,
    int tid, int lane, int wave, int l15, int quad, int q, int np,
    const short8 (&bfrag)[2][16],
    unsigned short (*sH)[520], float (*sG)[260])
{
  const int bbase = bb * 32;
  const int jbase = jw * 64;
  const int r  = tid >> 4;
  const int j0 = (tid & 15) * 4;
  float c[4] = {0.f, 0.f, 0.f, 0.f};

  for (int t = 0; t < TDIM; ++t) {
    const unsigned short* hsrc = (t & 1) ? hbuf1 : hbuf0;
    unsigned short* hdst = (t & 1) ? hbuf0 : hbuf1;

    // xg loads for step t (plain cached; in flight across poll + staging).
    const unsigned short* xgb = xg + (((size_t)t * 8 + bb) * 8 + jw) * 8192;
    ull xv64[4];
    #pragma unroll
    for (int qq = 0; qq < 4; ++qq)
      xv64[qq] = *(const ull*)(xgb + qq * 2048 + r * 64 + j0);

    // Poll (wave 0 only): all 8 producer-WG flags of this bb >= t.
    if (t > 0 && wave == 0) {
      const unsigned int* fp = flagbase + (lane & 7);
      int guard = 0;
      for (;;) {
        unsigned v = AG ? __hip_atomic_load(fp, __ATOMIC_RELAXED, __HIP_MEMORY_SCOPE_AGENT)
                        : flag_ld_sc0(fp);
        bool ok = (lane >= 8) || (v >= (unsigned)t);
        if ((__ballot(ok) & 0xFFull) == 0xFFull) break;
        if (++guard > (1 << 17)) break;   // safety valve: never hit when correct
        __builtin_amdgcn_s_sleep(1);
      }
    }
    __syncthreads();   // (a) release WG after poll

    // Stage h slice [32][512] bf16 (32 KB). Row = 512 bf16 = 128 ulls.
    const ull* src = (const ull*)hsrc + (size_t)bbase * 128;
    ull hv[8];
    if (AG) {
      #pragma unroll
      for (int i = 0; i < 8; ++i)
        hv[i] = __hip_atomic_load(src + i * 512 + tid, __ATOMIC_RELAXED,
                                  __HIP_MEMORY_SCOPE_AGENT);
    } else {
      ld_h8x_sc0(src + 0 * 512 + tid, src + 1 * 512 + tid,
                 src + 2 * 512 + tid, src + 3 * 512 + tid,
                 src + 4 * 512 + tid, src + 5 * 512 + tid,
                 src + 6 * 512 + tid, src + 7 * 512 + tid,
                 hv[0], hv[1], hv[2], hv[3], hv[4], hv[5], hv[6], hv[7]);
    }
    #pragma unroll
    for (int i = 0; i < 8; ++i) {
      int idx = i * 512 + tid;
      *(ull*)&sH[idx >> 7][(idx & 127) * 4] = hv[i];
    }
    __syncthreads();   // (b)

    // G-tile MFMA: 2 m-subtiles x 2 n-subtiles, K=512.
    f32x4 acc[2][2];
    acc[0][0] = acc[0][1] = acc[1][0] = acc[1][1] = (f32x4){0.f,0.f,0.f,0.f};
    #pragma unroll
    for (int ks = 0; ks < 16; ++ks) {
      int koff = ks * 32 + quad * 8;
      short8 a0 = *(const short8*)&sH[l15][koff];
      short8 a1 = *(const short8*)&sH[16 + l15][koff];
      acc[0][0] = __builtin_amdgcn_mfma_f32_16x16x32_bf16(a0, bfrag[0][ks], acc[0][0], 0, 0, 0);
      acc[1][0] = __builtin_amdgcn_mfma_f32_16x16x32_bf16(a1, bfrag[0][ks], acc[1][0], 0, 0, 0);
      acc[0][1] = __builtin_amdgcn_mfma_f32_16x16x32_bf16(a0, bfrag[1][ks], acc[0][1], 0, 0, 0);
      acc[1][1] = __builtin_amdgcn_mfma_f32_16x16x32_bf16(a1, bfrag[1][ks], acc[1][1], 0, 0, 0);
    }
    #pragma unroll
    for (int m = 0; m < 2; ++m)
      #pragma unroll
      for (int n2 = 0; n2 < 2; ++n2) {
        int col = q * 64 + (np + n2) * 16 + l15;
        #pragma unroll
        for (int rr = 0; rr < 4; ++rr)
          sG[m * 16 + quad * 4 + rr][col] = acc[m][n2][rr];
      }
    __syncthreads();   // (c)

    // Gate math: 4 cells (r, j0..j0+3).
    {
      float4 GI = *(const float4*)&sG[r][j0];
      float4 GF = *(const float4*)&sG[r][64 + j0];
      float4 GG = *(const float4*)&sG[r][128 + j0];
      float4 GO = *(const float4*)&sG[r][192 + j0];
      u16x4 xi  = __builtin_bit_cast(u16x4, xv64[0]);
      u16x4 xf  = __builtin_bit_cast(u16x4, xv64[1]);
      u16x4 xgv = __builtin_bit_cast(u16x4, xv64[2]);
      u16x4 xo  = __builtin_bit_cast(u16x4, xv64[3]);
      float gi[4] = {GI.x, GI.y, GI.z, GI.w};
      float gf[4] = {GF.x, GF.y, GF.z, GF.w};
      float gg[4] = {GG.x, GG.y, GG.z, GG.w};
      float go[4] = {GO.x, GO.y, GO.z, GO.w};
      float h4[4];
      #pragma unroll
      for (int k = 0; k < 4; ++k) {
        float vi = sigmoidf_fast(gi[k] + bf2f(xi[k]));
        float vf = sigmoidf_fast(gf[k] + bf2f(xf[k]));
        float vg = tanhf_fast   (gg[k] + bf2f(xgv[k]));
        float vo = sigmoidf_fast(go[k] + bf2f(xo[k]));
        c[k] = vf * c[k] + vi * vg;
        h4[k] = vo * tanhf_fast(c[k]);
      }
      ull hvout = (ull)f2bf(h4[0])
                | ((ull)f2bf(h4[1]) << 16)
                | ((ull)f2bf(h4[2]) << 32)
                | ((ull)f2bf(h4[3]) << 48);
      ull* dst = (ull*)hdst + (size_t)(bbase + r) * 128 + (jbase + j0) / 4;
      if (AG)
        __hip_atomic_store(dst, hvout, __ATOMIC_RELAXED, __HIP_MEMORY_SCOPE_AGENT);
      else
        st8_sc0(dst, hvout);
    }

    // (d) all h-stores of this WG acked at the coherence point, then flag.
    if (!AG) wait_vm0();    // explicit: compiler may not track asm stores
    __syncthreads();
    if (tid == 0) {
      if (AG)
        __hip_atomic_store(flagbase + jw, (unsigned)(t + 1), __ATOMIC_RELAXED,
                           __HIP_MEMORY_SCOPE_AGENT);
      else
        flag_st_sc0(flagbase + jw, (unsigned)(t + 1));
    }
  }
}

// ---------------------------------------------------------------------------
// Phase 2 driver: 64 WGs x 512 thr. Group bb = blockIdx&7: under round-robin
// dispatch all 8 members (blockIdx ≡ bb mod 8) land on ONE XCD -> sc0 path.
// Verified at runtime via HW_REG_XCC_ID handshake; fallback = agent scope.
// ---------------------------------------------------------------------------
__global__ void __launch_bounds__(512, 2) lstm_scan(
    const float* __restrict__ Whh, const unsigned short* __restrict__ xg,
    unsigned short* __restrict__ hbuf0, unsigned short* __restrict__ hbuf1,
    unsigned int* __restrict__ flags, unsigned int* __restrict__ xslot)
{
  __shared__ unsigned short sH[32][520];   // h slice, +8 pad
  __shared__ float sG[32][260];            // gates, +4 pad
  __shared__ unsigned sFast;

  const int tid  = threadIdx.x;
  const int lane = tid & 63;
  const int wave = tid >> 6;        // 0..7
  const int l15  = lane & 15;
  const int quad = lane >> 4;
  const int q    = wave >> 1;       // gate (i,f,g,o)
  const int np   = (wave & 1) * 2;  // n-subtile pair
  const int bb = blockIdx.x & 7;    // batch block; members share XCD (expected)
  const int jw = blockIdx.x >> 3;   // col block 0..7

  // Publish my XCD id (HW_REG_XCC_ID = hwreg id 20, offset 0, size 8
  // -> simm16 = (8-1)<<11 | 0<<6 | 20 = 0x3814). m09-verified on MI355X.
  unsigned myxcd = __builtin_amdgcn_s_getreg(0x3814) & 0xFFu;
  if (tid == 0)
    __hip_atomic_store(xslot + blockIdx.x, 0x100u | myxcd,
                       __ATOMIC_RELAXED, __HIP_MEMORY_SCOPE_AGENT);

  // One-time: W_hh -> 2x16 register B-frags per lane (128 VGPRs).
  short8 bfrag[2][16];
  #pragma unroll
  for (int n2 = 0; n2 < 2; ++n2) {
    const float* wrow = Whh + (size_t)(q * 512 + jw * 64 + (np + n2) * 16 + l15) * 512;
    #pragma unroll
    for (int ks = 0; ks < 16; ++ks) {
      const float* p = wrow + ks * 32 + quad * 8;
      float4 f0 = ((const float4*)p)[0];
      float4 f1 = ((const float4*)p)[1];
      short8 v;
      v[0] = (short)f2bf(f0.x); v[1] = (short)f2bf(f0.y);
      v[2] = (short)f2bf(f0.z); v[3] = (short)f2bf(f0.w);
      v[4] = (short)f2bf(f1.x); v[5] = (short)f2bf(f1.y);
      v[6] = (short)f2bf(f1.z); v[7] = (short)f2bf(f1.w);
      bfrag[n2][ks] = v;
    }
  }

  // Group verdict: all 8 members of group bb on the same XCD?
  if (wave == 0) {
    const unsigned* sp = xslot + bb + 8 * (lane & 7);   // members: bb + 8*jw
    unsigned v = 0;
    int guard = 0;
    bool lived = true;
    for (;;) {
      v = __hip_atomic_load(sp, __ATOMIC_RELAXED, __HIP_MEMORY_SCOPE_AGENT);
      if (__ballot(v >= 0x100u) == ~0ull) break;
      if (++guard > (1 << 20)) { lived = false; break; }
      __builtin_amdgcn_s_sleep(1);
    }
    unsigned ref = (unsigned)__shfl((int)v, 0);
    bool same = lived && (__ballot(v == ref) == ~0ull);
    if (lane == 0) sFast = same ? 1u : 0u;
  }
  __syncthreads();
  const bool fast = (sFast != 0);

  unsigned int* flagbase = flags + bb * 32;   // 8 flags/group, 128B apart

  if (fast)
    scan_steps<false>(xg, hbuf0, hbuf1, flagbase, bb, jw,
                      tid, lane, wave, l15, quad, q, np, bfrag, sH, sG);
  else
    scan_steps<true>(xg, hbuf0, hbuf1, flagbase, bb, jw,
                     tid, lane, wave, l15, quad, q, np, bfrag, sH, sG);
}

// ---------------------------------------------------------------------------
// Head: out[b] = h_last[b,:] . fc_w + fc_b
// ---------------------------------------------------------------------------
__global__ void head_kernel(const unsigned short* __restrict__ h,
                            const float* __restrict__ fc_w,
                            const float* __restrict__ fc_b,
                            float* __restrict__ out)
{
  const int b = blockIdx.x;
  const int lane = threadIdx.x;
  const unsigned short* hr = h + (size_t)b * 512;
  float s = 0.f;
  #pragma unroll
  for (int i = 0; i < 8; ++i) {
    int idx = lane + i * 64;
    s += bf2f(hr[idx]) * fc_w[idx];
  }
  #pragma unroll
  for (int off = 32; off > 0; off >>= 1) s += __shfl_down(s, off);
  if (lane == 0) out[b] = s + fc_b[0];
}

// ---------------------------------------------------------------------------
extern "C" void kernel_launch(void* const* d_in, const int* in_sizes, int n_in,
                              void* d_out, int out_size, void* d_ws, size_t ws_size,
                              hipStream_t stream) {
  const float* x    = (const float*)d_in[0];
  const float* W_ih = (const float*)d_in[1];
  const float* W_hh = (const float*)d_in[2];
  const float* b_ih = (const float*)d_in[3];
  const float* b_hh = (const float*)d_in[4];
  const float* fc_w = (const float*)d_in[5];
  const float* fc_b = (const float*)d_in[6];
  float* out = (float*)d_out;

  // Workspace layout:
  //   [0, 268435456)   xg bf16 (scan-blocked)
  //   + hbuf0 (256KB), hbuf1 (256KB), flags (4KB), xslot (4KB)
  //   [fast GEMM only] xb bf16 (64MB), wb bf16 (2MB)
  const size_t XG = (size_t)BDIM * TDIM * G4 * 2;   // 268435456
  const size_t HB = (size_t)BDIM * HDIM * 2;        // 262144
  char* ws = (char*)d_ws;
  unsigned short* xg    = (unsigned short*)ws;
  unsigned short* hbuf0 = (unsigned short*)(ws + XG);
  unsigned short* hbuf1 = (unsigned short*)(ws + XG + HB);
  unsigned int*   flags = (unsigned int*)(ws + XG + 2 * HB);
  unsigned int*   xslot = (unsigned int*)(ws + XG + 2 * HB + 4096);
  const size_t XB_OFF = XG + 2 * HB + 8192;
  const size_t WB_OFF = XB_OFF + (size_t)BDIM * TDIM * IDIM * 2;  // +64MB
  const size_t NEED   = WB_OFF + (size_t)G4 * IDIM * 2;           // +2MB

  // Zero hbuf0 (h0) + flags + xslot (ws poisoned 0xAA each call).
  hipMemsetAsync(ws + XG, 0, HB, stream);
  hipMemsetAsync(ws + XG + 2 * HB, 0, 8192, stream);

  if (ws_size >= NEED) {
    unsigned short* xb = (unsigned short*)(ws + XB_OFF);
    unsigned short* wb = (unsigned short*)(ws + WB_OFF);
    convert_bf16<<<16896, 256, 0, stream>>>(x, W_ih, xb, wb);
    xg_gemm_bf16<<<8192, 256, 0, stream>>>(xb, wb, b_ih, b_hh, xg);
  } else {
    xg_gemm_f32<<<dim3(16, 512), 256, 0, stream>>>(x, W_ih, b_ih, b_hh, xg);
  }
  lstm_scan<<<64, 512, 0, stream>>>(W_hh, xg, hbuf0, hbuf1, flags, xslot);
  // T=256: final write (t=255, odd) went to hbuf0.
  head_kernel<<<BDIM, 64, 0, stream>>>(hbuf0, fc_w, fc_b, out);
}